// Round 18
// baseline (173.794 us; speedup 1.0000x reference)
//
#include <hip/hip_runtime.h>
#include <hip/hip_bf16.h>
#include <hip/hip_fp16.h>
#include <math.h>

#define M_ROWS 32768
#define NE 2048
#define EDIM 128

// d_out element offsets (fp32)
#define O_LOSS 0
#define O_ZQ 1
#define O_PERP 4194305
#define O_MINENC 4194306
#define O_IDX 71303170ll

#define AS1 __attribute__((address_space(1)))
#define AS3 __attribute__((address_space(3)))

typedef unsigned short u16;
typedef __attribute__((ext_vector_type(8))) _Float16 half8;  // 8 f16 (4 VGPRs)
typedef __attribute__((ext_vector_type(16))) float f32x16;   // 32x32 MFMA acc

#define ZPLANE2 4194304   // 32768*128 (u16 elems per z plane)

// async global->LDS DMA, 16B/lane; LDS dest = wave-uniform base + lane*16.
__device__ __forceinline__ void gload16u(const u16* g, u16* l) {
    __builtin_amdgcn_global_load_lds((const AS1 void*)g, (AS3 void*)l, 16, 0, 0);
}

// ---------------- prep_z: 2-level fp16 split of z + fused zsums (proven) ---------
__global__ __launch_bounds__(256) void prep_z_kernel(const float* __restrict__ z,
                                                     u16* __restrict__ z2,
                                                     float* __restrict__ zsums) {
    const int tid = threadIdx.x;
    const int rl = tid >> 4;        // row within block (16)
    const int sub = tid & 15;       // 8-elem group within row
    const int row = blockIdx.x * 16 + rl;
    const float* zr = z + (size_t)row * EDIM + sub * 8;
    float4 v0 = reinterpret_cast<const float4*>(zr)[0];
    float4 v1 = reinterpret_cast<const float4*>(zr)[1];
    float fv[8] = {v0.x, v0.y, v0.z, v0.w, v1.x, v1.y, v1.z, v1.w};
    u16 hs[8], ms[8];
    float s = 0.0f;
    #pragma unroll
    for (int j = 0; j < 8; j++) {
        s += fv[j] * fv[j];
        __half hh = __float2half_rn(fv[j]);
        float fh = __half2float(hh);
        float r = fv[j] - fh;                  // exact
        __half hm = __float2half_rn(r);
        hs[j] = __half_as_ushort(hh);
        ms[j] = __half_as_ushort(hm);
    }
    size_t off = (size_t)row * EDIM + sub * 8;
    reinterpret_cast<ushort4*>(z2 + off)[0] = make_ushort4(hs[0], hs[1], hs[2], hs[3]);
    reinterpret_cast<ushort4*>(z2 + off + 4)[0] = make_ushort4(hs[4], hs[5], hs[6], hs[7]);
    reinterpret_cast<ushort4*>(z2 + (size_t)ZPLANE2 + off)[0] = make_ushort4(ms[0], ms[1], ms[2], ms[3]);
    reinterpret_cast<ushort4*>(z2 + (size_t)ZPLANE2 + off + 4)[0] = make_ushort4(ms[4], ms[5], ms[6], ms[7]);
    #pragma unroll
    for (int o = 8; o >= 1; o >>= 1) s += __shfl_xor(s, o);
    if (sub == 0) zsums[row] = s;
}

// ---------------- prep_e: eq (bit-identical tree) + hist zero + e2p pack ---------
__global__ void prep_e_kernel(const float* __restrict__ emb, float* __restrict__ eq,
                              int* __restrict__ hist, u16* __restrict__ e2p) {
    const int n = blockIdx.x;
    const int lane = threadIdx.x;
    float v0 = emb[(size_t)n * EDIM + lane];
    float v1 = emb[(size_t)n * EDIM + 64 + lane];
    float s = v0 * v0 + v1 * v1;
    #pragma unroll
    for (int off = 32; off >= 1; off >>= 1) s += __shfl_down(s, off);
    if (lane == 0) { eq[n] = s; hist[n] = 0; }

    if (lane < 32) {
        const int k = lane * 4;
        float4 e4 = reinterpret_cast<const float4*>(emb + (size_t)n * EDIM + k)[0];
        float fv[4] = {e4.x * 2048.0f, e4.y * 2048.0f, e4.z * 2048.0f, e4.w * 2048.0f};
        u16 hs[4], ms[4];
        #pragma unroll
        for (int j = 0; j < 4; j++) {
            __half hh = __float2half_rn(fv[j]);
            float fh = __half2float(hh);
            float r = fv[j] - fh;                  // exact
            __half hm = __float2half_rn(r);
            hs[j] = __half_as_ushort(hh);
            ms[j] = __half_as_ushort(hm);
        }
        const int strip = n >> 5, r32n = n & 31;
        const int jj = k >> 4, hh2 = (k >> 3) & 1, slot4 = k & 7;
        size_t base = ((size_t)(strip * 8 + jj) * 2) * 512 + (size_t)(hh2 * 32 + r32n) * 8 + slot4;
        reinterpret_cast<ushort4*>(e2p + base)[0]       = make_ushort4(hs[0], hs[1], hs[2], hs[3]);
        reinterpret_cast<ushort4*>(e2p + base + 512)[0] = make_ushort4(ms[0], ms[1], ms[2], ms[3]);
    }
}

// ---------------- MFMA argmin: 8 compute waves + 4 store waves, 1 block/CU -------
// 768 threads = 12 waves: deliberately > the 2-block residency limit, so exactly
// 1 block/CU (deterministic -- round-17's 5-wave block fell to 1 block/CU with
// only 4 compute waves; here compute density matches round 16's 8 waves/CU).
// Compute waves 0-7: BIT-IDENTICAL value path (8 col-groups x 256-col tiles,
// round-13-proven e2p indexing); pure-load main loop -- their vmcnt never sees
// store acks. Store waves 8-11: stream the 512KB minenc zero-fill, issued right
// after barrier 1 (zero outstanding at barrier 1 -> no drain), 4x63 in-flight.
// Barrier 2 drains their acks (overlapped with compute) before the 1.0 writes.
template<int WE>
__global__ __launch_bounds__(768, 3) void argmin_mfma_kernel(
    const u16* __restrict__ z2, const u16* __restrict__ e2p,
    const float* __restrict__ zsums, const float* __restrict__ eq,
    int* __restrict__ out_idx, float* __restrict__ out, int* __restrict__ hist,
    const float* __restrict__ z, const float* __restrict__ emb,
    float* __restrict__ part)
{
    __shared__ __align__(16) u16 zs[16384];     // 32 KB
    __shared__ float zsl[64];
    __shared__ float cand_v[512];               // 64 rows x 8 wn
    __shared__ int   cand_i[512];
    __shared__ int   ids[64];
    __shared__ float red[768];

    const int tid = threadIdx.x;
    const int w = tid >> 6, l = tid & 63;
    const int wn = w;                   // col group 0..7 (compute waves)
    const int h = l >> 5, r32 = l & 31;
    const int m0 = blockIdx.x * 64;

    float2* me2 = reinterpret_cast<float2*>(out + O_MINENC + (size_t)m0 * NE);

    // prologue: compute waves DMA zs (2 levels, full K) -- 4 gloads/thread
    if (w < 8) {
        #pragma unroll
        for (int jj = 0; jj < 4; jj++) {
            int s0 = jj * 512 + w * 64;          // wave-uniform slot base
            int s = s0 + l;
            int lv = s >> 10, kc = (s >> 6) & 15, row = s & 63;
            gload16u(z2 + (size_t)lv * ZPLANE2 + ((size_t)(m0 + row) << 7) + kc * 8,
                     zs + s0 * 8);
        }
    }
    if (tid < 64) zsl[tid] = zsums[m0 + tid];
    __syncthreads();    // zs + zsl ready; store waves have nothing outstanding

    if (w < 8) {        // ================= compute waves =================
        float best[2][16];
        int   bidx[2][16];
        #pragma unroll
        for (int i2 = 0; i2 < 2; i2++)
            #pragma unroll
            for (int q = 0; q < 16; q++) { best[i2][q] = 3.4e38f; bidx[i2][q] = 0; }

        for (int tt = 0; tt < 8; tt++) {        // 8 t-tiles x 256 cols
            const int strip = tt * 8 + wn;
            const u16* bb = e2p + (size_t)strip * 8192 + (size_t)l * 8;
            const int n = tt * 256 + wn * 32 + r32;
            const float eqv = eq[n];

            f32x16 am[2], ac[2];
            #pragma unroll
            for (int i2 = 0; i2 < 2; i2++)
                #pragma unroll
                for (int q = 0; q < 16; q++) { am[i2][q] = 0.0f; ac[i2][q] = 0.0f; }

            #pragma unroll 4
            for (int j = 0; j < 8; j++) {       // K=16 per step, k ascending
                half8 b0 = *reinterpret_cast<const half8*>(bb + (size_t)(j * 2 + 0) * 512);
                half8 b1 = *reinterpret_cast<const half8*>(bb + (size_t)(j * 2 + 1) * 512);
                half8 a00 = *reinterpret_cast<const half8*>(zs + ((0 * 16 + j * 2 + h) * 64 + 0 * 32 + r32) * 8);
                half8 a01 = *reinterpret_cast<const half8*>(zs + ((1 * 16 + j * 2 + h) * 64 + 0 * 32 + r32) * 8);
                half8 a10 = *reinterpret_cast<const half8*>(zs + ((0 * 16 + j * 2 + h) * 64 + 1 * 32 + r32) * 8);
                half8 a11 = *reinterpret_cast<const half8*>(zs + ((1 * 16 + j * 2 + h) * 64 + 1 * 32 + r32) * 8);

                am[0] = __builtin_amdgcn_mfma_f32_32x32x16_f16(a00, b0, am[0], 0, 0, 0);
                ac[0] = __builtin_amdgcn_mfma_f32_32x32x16_f16(a00, b1, ac[0], 0, 0, 0);
                ac[0] = __builtin_amdgcn_mfma_f32_32x32x16_f16(a01, b0, ac[0], 0, 0, 0);
                am[1] = __builtin_amdgcn_mfma_f32_32x32x16_f16(a10, b0, am[1], 0, 0, 0);
                ac[1] = __builtin_amdgcn_mfma_f32_32x32x16_f16(a10, b1, ac[1], 0, 0, 0);
                ac[1] = __builtin_amdgcn_mfma_f32_32x32x16_f16(a11, b0, ac[1], 0, 0, 0);
            }

            // online argmin update (n ascending across tt; strict <)
            #pragma unroll
            for (int i2 = 0; i2 < 2; i2++) {
                #pragma unroll
                for (int q = 0; q < 16; q++) {
                    const int row = i2 * 32 + ((q & 3) + 8 * (q >> 2) + 4 * h);
                    float zse = zsl[row] + eqv;              // fp32 round at ~128 scale
                    float dotp = am[i2][q] + ac[i2][q];      // one round
                    float val = zse - dotp * 0.0009765625f;  // *2^-10 exact; one round
                    if (val < best[i2][q]) { best[i2][q] = val; bidx[i2][q] = n; }
                }
            }
        }

        // reduce over the 32 col-lanes (offs <32 stay within each half)
        #pragma unroll
        for (int off = 16; off >= 1; off >>= 1) {
            #pragma unroll
            for (int i2 = 0; i2 < 2; i2++)
                #pragma unroll
                for (int q = 0; q < 16; q++) {
                    float ov = __shfl_xor(best[i2][q], off);
                    int   oi = __shfl_xor(bidx[i2][q], off);
                    if (ov < best[i2][q] || (ov == best[i2][q] && oi < bidx[i2][q])) {
                        best[i2][q] = ov; bidx[i2][q] = oi;
                    }
                }
        }
        if (r32 == 0) {        // lanes 0 and 32 per wave
            #pragma unroll
            for (int i2 = 0; i2 < 2; i2++)
                #pragma unroll
                for (int q = 0; q < 16; q++) {
                    int row = i2 * 32 + ((q & 3) + 8 * (q >> 2) + 4 * h);
                    cand_v[row * 8 + wn] = best[i2][q];
                    cand_i[row * 8 + wn] = bidx[i2][q];
                }
        }
    } else {            // ================= store waves (8-11) =================
        if constexpr (WE) {
            const int ws = w - 8;               // quarter of the 64x2048 zero-fill
            const float2 zz2 = make_float2(0.0f, 0.0f);
            #pragma unroll 8
            for (int i = 0; i < 256; i++)       // 256 x 512B contiguous stores
                me2[(ws * 256 + i) * 64 + l] = zz2;
        }
    }

    __syncthreads();    // cand ready; store-wave acks drained (overlapped)

    if (tid < 64) {     // final: 8 wn-candidates; explicit idx tie-break
        float bv = cand_v[tid * 8 + 0];
        int   bi = cand_i[tid * 8 + 0];
        #pragma unroll
        for (int j = 1; j < 8; j++) {
            float v = cand_v[tid * 8 + j];
            int   ii = cand_i[tid * 8 + j];
            if (v < bv || (v == bv && ii < bi)) { bv = v; bi = ii; }
        }
        ids[tid] = bi;
        out_idx[m0 + tid] = bi;
        out[O_IDX + m0 + tid] = (float)bi;
        atomicAdd(&hist[bi], 1);
        if constexpr (WE)
            out[O_MINENC + (size_t)(m0 + tid) * NE + bi] = 1.0f;
    }
    __syncthreads();    // ids visible

    // ---- fused gather: z_q_st for our 64 rows + loss partial ----
    float s = 0.0f;
    if (tid < 512) {
        #pragma unroll
        for (int j = 0; j < 2; j++) {          // 1024 8-float units / 512 threads
            int u = j * 512 + tid;
            int r = u >> 4, sub = u & 15;
            int id = ids[r];
            const float* zr = z + (size_t)(m0 + r) * EDIM + sub * 8;
            const float* er = emb + (size_t)id * EDIM + sub * 8;
            float* outr = out + O_ZQ + (size_t)(m0 + r) * EDIM + sub * 8;
            float4 z0 = reinterpret_cast<const float4*>(zr)[0];
            float4 z1 = reinterpret_cast<const float4*>(zr)[1];
            float4 e0 = reinterpret_cast<const float4*>(er)[0];
            float4 e1 = reinterpret_cast<const float4*>(er)[1];
            float zz[8] = {z0.x, z0.y, z0.z, z0.w, z1.x, z1.y, z1.z, z1.w};
            float ee[8] = {e0.x, e0.y, e0.z, e0.w, e1.x, e1.y, e1.z, e1.w};
            #pragma unroll
            for (int jj = 0; jj < 8; jj++) {
                float d = ee[jj] - zz[jj];
                outr[jj] = zz[jj] + d;         // match reference rounding
                s += d * d;
            }
        }
    }
    red[tid] = s;
    __syncthreads();
    if (tid < 256) red[tid] = red[tid] + red[tid + 256] + red[tid + 512];
    __syncthreads();
    #pragma unroll
    for (int o = 128; o >= 1; o >>= 1) {
        if (tid < o) red[tid] += red[tid + o];
        __syncthreads();
    }
    if (tid == 0) part[blockIdx.x] = red[0];
}

// ---------------- min_encodings one-hot fill (fallback path only) ----------------
__global__ __launch_bounds__(256) void minenc_kernel(const int* __restrict__ idx,
                                                     float* __restrict__ out) {
    size_t i = (size_t)blockIdx.x * blockDim.x + threadIdx.x;
    const size_t total = (size_t)M_ROWS * (NE / 2);
    const size_t stride = (size_t)gridDim.x * blockDim.x;
    for (; i < total; i += stride) {
        int row = (int)(i >> 10);
        int col = (int)(i & 1023) << 1;
        int id = idx[row];
        float2 v;
        v.x = (col == id) ? 1.0f : 0.0f;
        v.y = (col + 1 == id) ? 1.0f : 0.0f;
        reinterpret_cast<float2*>(out)[i] = v;
    }
}

// ---------------- finalize: loss + perplexity (512 partials) ----------------------
__global__ __launch_bounds__(256) void finalize_kernel(const float* __restrict__ partial,
                                                       const int* __restrict__ hist,
                                                       float* __restrict__ out) {
    __shared__ float red[256];
    const int tid = threadIdx.x;
    float s = partial[tid] + partial[tid + 256];
    red[tid] = s;
    __syncthreads();
    #pragma unroll
    for (int o = 128; o >= 1; o >>= 1) {
        if (tid < o) red[tid] += red[tid + o];
        __syncthreads();
    }
    if (tid == 0) out[O_LOSS] = 1.25f * red[0] / (float)((size_t)M_ROWS * EDIM);
    __syncthreads();

    float h = 0.0f;
    for (int i = 0; i < 8; i++) {
        float p = (float)hist[tid * 8 + i] * (1.0f / (float)M_ROWS);
        h += p * logf(p + 1e-10f);
    }
    red[tid] = h;
    __syncthreads();
    #pragma unroll
    for (int o = 128; o >= 1; o >>= 1) {
        if (tid < o) red[tid] += red[tid + o];
        __syncthreads();
    }
    if (tid == 0) out[O_PERP] = expf(-red[0]);
}

extern "C" void kernel_launch(void* const* d_in, const int* in_sizes, int n_in,
                              void* d_out, int out_size, void* d_ws, size_t ws_size,
                              hipStream_t stream) {
    const float* z   = (const float*)d_in[0];
    const float* emb = (const float*)d_in[1];
    float* out = (float*)d_out;

    char* ws = (char*)d_ws;
    float* eq    = (float*)ws;                    // 2048 f32
    int*   idx   = (int*)(ws + 8192);             // 32768 i32
    int*   hist  = (int*)(ws + 139264);           // 2048 i32
    float* part  = (float*)(ws + 147456);         // 512 f32
    float* zsums = (float*)(ws + 155648);         // 32768 f32

    const bool big_ws = (ws_size >= (size_t)(40u << 20));   // fixed per session
    u16 *Z2, *E2P;
    if (big_ws) {                                 // planes + packed B in scratch
        Z2  = (u16*)(ws + (4u << 20));            // 16 MB (2 planes)
        E2P = (u16*)(ws + (24u << 20));           // 1 MB packed B-frags
    } else {                                      // fallback: use minenc region,
        Z2  = (u16*)(out + O_MINENC + 2);         // minenc kernel rewrites after
        E2P = Z2 + 2 * (size_t)ZPLANE2;
    }

    prep_z_kernel<<<2048, 256, 0, stream>>>(z, Z2, zsums);
    prep_e_kernel<<<NE, 64, 0, stream>>>(emb, eq, hist, E2P);
    if (big_ws) {
        argmin_mfma_kernel<1><<<512, 768, 0, stream>>>(Z2, E2P, zsums, eq, idx, out, hist, z, emb, part);
    } else {
        argmin_mfma_kernel<0><<<512, 768, 0, stream>>>(Z2, E2P, zsums, eq, idx, out, hist, z, emb, part);
        minenc_kernel<<<8192, 256, 0, stream>>>(idx, out + O_MINENC);
    }
    finalize_kernel<<<1, 256, 0, stream>>>(part, hist, out);
}

// Round 19
// 134.411 us; speedup vs baseline: 1.2930x; 1.2930x over previous
//
#include <hip/hip_runtime.h>
#include <hip/hip_bf16.h>
#include <hip/hip_fp16.h>
#include <math.h>

#define M_ROWS 32768
#define NE 2048
#define EDIM 128

// d_out element offsets (fp32)
#define O_LOSS 0
#define O_ZQ 1
#define O_PERP 4194305
#define O_MINENC 4194306
#define O_IDX 71303170ll

#define AS1 __attribute__((address_space(1)))
#define AS3 __attribute__((address_space(3)))

typedef unsigned short u16;
typedef __attribute__((ext_vector_type(8))) _Float16 half8;  // 8 f16 (4 VGPRs)
typedef __attribute__((ext_vector_type(16))) float f32x16;   // 32x32 MFMA acc

#define ZPLANE2 4194304   // 32768*128 (u16 elems per z plane)

// async global->LDS DMA, 16B/lane; LDS dest = wave-uniform base + lane*16.
__device__ __forceinline__ void gload16u(const u16* g, u16* l) {
    __builtin_amdgcn_global_load_lds((const AS1 void*)g, (AS3 void*)l, 16, 0, 0);
}

// ---------------- prep_z: 2-level fp16 split of z + fused zsums (proven) ---------
__global__ __launch_bounds__(256) void prep_z_kernel(const float* __restrict__ z,
                                                     u16* __restrict__ z2,
                                                     float* __restrict__ zsums) {
    const int tid = threadIdx.x;
    const int rl = tid >> 4;        // row within block (16)
    const int sub = tid & 15;       // 8-elem group within row
    const int row = blockIdx.x * 16 + rl;
    const float* zr = z + (size_t)row * EDIM + sub * 8;
    float4 v0 = reinterpret_cast<const float4*>(zr)[0];
    float4 v1 = reinterpret_cast<const float4*>(zr)[1];
    float fv[8] = {v0.x, v0.y, v0.z, v0.w, v1.x, v1.y, v1.z, v1.w};
    u16 hs[8], ms[8];
    float s = 0.0f;
    #pragma unroll
    for (int j = 0; j < 8; j++) {
        s += fv[j] * fv[j];
        __half hh = __float2half_rn(fv[j]);
        float fh = __half2float(hh);
        float r = fv[j] - fh;                  // exact
        __half hm = __float2half_rn(r);
        hs[j] = __half_as_ushort(hh);
        ms[j] = __half_as_ushort(hm);
    }
    size_t off = (size_t)row * EDIM + sub * 8;
    reinterpret_cast<ushort4*>(z2 + off)[0] = make_ushort4(hs[0], hs[1], hs[2], hs[3]);
    reinterpret_cast<ushort4*>(z2 + off + 4)[0] = make_ushort4(hs[4], hs[5], hs[6], hs[7]);
    reinterpret_cast<ushort4*>(z2 + (size_t)ZPLANE2 + off)[0] = make_ushort4(ms[0], ms[1], ms[2], ms[3]);
    reinterpret_cast<ushort4*>(z2 + (size_t)ZPLANE2 + off + 4)[0] = make_ushort4(ms[4], ms[5], ms[6], ms[7]);
    #pragma unroll
    for (int o = 8; o >= 1; o >>= 1) s += __shfl_xor(s, o);
    if (sub == 0) zsums[row] = s;
}

// ---------------- prep_e: eq (bit-identical tree) + hist zero + e2p pack ---------
__global__ void prep_e_kernel(const float* __restrict__ emb, float* __restrict__ eq,
                              int* __restrict__ hist, u16* __restrict__ e2p) {
    const int n = blockIdx.x;
    const int lane = threadIdx.x;
    float v0 = emb[(size_t)n * EDIM + lane];
    float v1 = emb[(size_t)n * EDIM + 64 + lane];
    float s = v0 * v0 + v1 * v1;
    #pragma unroll
    for (int off = 32; off >= 1; off >>= 1) s += __shfl_down(s, off);
    if (lane == 0) { eq[n] = s; hist[n] = 0; }

    if (lane < 32) {
        const int k = lane * 4;
        float4 e4 = reinterpret_cast<const float4*>(emb + (size_t)n * EDIM + k)[0];
        float fv[4] = {e4.x * 2048.0f, e4.y * 2048.0f, e4.z * 2048.0f, e4.w * 2048.0f};
        u16 hs[4], ms[4];
        #pragma unroll
        for (int j = 0; j < 4; j++) {
            __half hh = __float2half_rn(fv[j]);
            float fh = __half2float(hh);
            float r = fv[j] - fh;                  // exact
            __half hm = __float2half_rn(r);
            hs[j] = __half_as_ushort(hh);
            ms[j] = __half_as_ushort(hm);
        }
        const int strip = n >> 5, r32n = n & 31;
        const int jj = k >> 4, hh2 = (k >> 3) & 1, slot4 = k & 7;
        size_t base = ((size_t)(strip * 8 + jj) * 2) * 512 + (size_t)(hh2 * 32 + r32n) * 8 + slot4;
        reinterpret_cast<ushort4*>(e2p + base)[0]       = make_ushort4(hs[0], hs[1], hs[2], hs[3]);
        reinterpret_cast<ushort4*>(e2p + base + 512)[0] = make_ushort4(ms[0], ms[1], ms[2], ms[3]);
    }
}

// ---------------- MFMA argmin: round-16 core + hoisted/staggered zero-fill -------
// EXACT round-16 shape (256 thr, launch_bounds(256,2), 2 blocks/CU, VGPR ~124).
// Change: the 512KB minenc zero-fill is hoisted OUT of the tt loop (it depends on
// nothing), so the main loop is PURE LOADS -- no tt's B-load wait ever drains
// store acks (in-order vmcnt). Staggered by grid half: blocks 0-255 store BEFORE
// the loop (their drain overlaps the co-resident partner block's compute; under
// round-robin dispatch block b and b+256 share a CU), blocks 256-511 store AFTER
// (drain at the join barrier overlaps the partner's compute). Value path is
// BIT-IDENTICAL to rounds 9-16.
template<int WE>
__global__ __launch_bounds__(256, 2) void argmin_mfma_kernel(
    const u16* __restrict__ z2, const u16* __restrict__ e2p,
    const float* __restrict__ zsums, const float* __restrict__ eq,
    int* __restrict__ out_idx, float* __restrict__ out, int* __restrict__ hist,
    const float* __restrict__ z, const float* __restrict__ emb,
    float* __restrict__ part)
{
    __shared__ __align__(16) u16 zs[16384];     // 32 KB
    __shared__ float zsl[64];
    __shared__ float cand_v[256];
    __shared__ int   cand_i[256];
    __shared__ int   ids[64];
    __shared__ float red[256];

    const int tid = threadIdx.x;
    const int w = tid >> 6, l = tid & 63;
    const int wn = w;                   // col quarter within the 128-col tt tile
    const int h = l >> 5, r32 = l & 31;
    const int m0 = blockIdx.x * 64;
    const bool store_first = ((blockIdx.x >> 8) & 1) == 0;

    float2* me2 = reinterpret_cast<float2*>(out + O_MINENC + (size_t)m0 * NE);

    // prologue: DMA zs (2 levels, full K) -- 8 gloads/thread
    #pragma unroll
    for (int jj = 0; jj < 8; jj++) {
        int s0 = jj * 256 + w * 64;              // wave-uniform slot base
        int s = s0 + l;
        int lv = s >> 10, kc = (s >> 6) & 15, row = s & 63;
        gload16u(z2 + (size_t)lv * ZPLANE2 + ((size_t)(m0 + row) << 7) + kc * 8,
                 zs + s0 * 8);
    }
    if (tid < 64) zsl[tid] = zsums[m0 + tid];
    __syncthreads();    // drains vmcnt: zs + zsl ready

    if constexpr (WE) {                 // first grid-half: zero-fill BEFORE loop
        if (store_first) {
            const float2 zz2 = make_float2(0.0f, 0.0f);
            #pragma unroll 8
            for (int i = 0; i < 256; i++)       // 64 rows x 2048 zeros, coalesced
                me2[i * 256 + tid] = zz2;
        }
    }

    float best[2][16];
    int   bidx[2][16];
    #pragma unroll
    for (int i2 = 0; i2 < 2; i2++)
        #pragma unroll
        for (int q = 0; q < 16; q++) { best[i2][q] = 3.4e38f; bidx[i2][q] = 0; }

    for (int tt = 0; tt < 16; tt++) {           // 16 t-tiles x 128 cols, PURE LOADS
        const int strip = tt * 4 + wn;
        const u16* bb = e2p + ((size_t)strip * 16) * 512 + (size_t)l * 8;
        const int n = tt * 128 + wn * 32 + r32;
        const float eqv = eq[n];

        f32x16 am[2], ac[2];
        #pragma unroll
        for (int i2 = 0; i2 < 2; i2++)
            #pragma unroll
            for (int q = 0; q < 16; q++) { am[i2][q] = 0.0f; ac[i2][q] = 0.0f; }

        #pragma unroll 4
        for (int j = 0; j < 8; j++) {           // K=16 per step, k ascending
            half8 b0 = *reinterpret_cast<const half8*>(bb + (size_t)(j * 2 + 0) * 512);
            half8 b1 = *reinterpret_cast<const half8*>(bb + (size_t)(j * 2 + 1) * 512);
            half8 a00 = *reinterpret_cast<const half8*>(zs + ((0 * 16 + j * 2 + h) * 64 + 0 * 32 + r32) * 8);
            half8 a01 = *reinterpret_cast<const half8*>(zs + ((1 * 16 + j * 2 + h) * 64 + 0 * 32 + r32) * 8);
            half8 a10 = *reinterpret_cast<const half8*>(zs + ((0 * 16 + j * 2 + h) * 64 + 1 * 32 + r32) * 8);
            half8 a11 = *reinterpret_cast<const half8*>(zs + ((1 * 16 + j * 2 + h) * 64 + 1 * 32 + r32) * 8);

            am[0] = __builtin_amdgcn_mfma_f32_32x32x16_f16(a00, b0, am[0], 0, 0, 0);
            ac[0] = __builtin_amdgcn_mfma_f32_32x32x16_f16(a00, b1, ac[0], 0, 0, 0);
            ac[0] = __builtin_amdgcn_mfma_f32_32x32x16_f16(a01, b0, ac[0], 0, 0, 0);
            am[1] = __builtin_amdgcn_mfma_f32_32x32x16_f16(a10, b0, am[1], 0, 0, 0);
            ac[1] = __builtin_amdgcn_mfma_f32_32x32x16_f16(a10, b1, ac[1], 0, 0, 0);
            ac[1] = __builtin_amdgcn_mfma_f32_32x32x16_f16(a11, b0, ac[1], 0, 0, 0);
        }

        // online argmin update (n ascending across tt; strict <)
        #pragma unroll
        for (int i2 = 0; i2 < 2; i2++) {
            #pragma unroll
            for (int q = 0; q < 16; q++) {
                const int row = i2 * 32 + ((q & 3) + 8 * (q >> 2) + 4 * h);
                float zse = zsl[row] + eqv;              // fp32 round at ~128 scale
                float dotp = am[i2][q] + ac[i2][q];      // one round
                float val = zse - dotp * 0.0009765625f;  // *2^-10 exact; one round
                if (val < best[i2][q]) { best[i2][q] = val; bidx[i2][q] = n; }
            }
        }
    }

    if constexpr (WE) {                 // second grid-half: zero-fill AFTER loop
        if (!store_first) {
            const float2 zz2 = make_float2(0.0f, 0.0f);
            #pragma unroll 8
            for (int i = 0; i < 256; i++)
                me2[i * 256 + tid] = zz2;
        }
    }

    // reduce over the 32 col-lanes (offs <32 stay within each half)
    #pragma unroll
    for (int off = 16; off >= 1; off >>= 1) {
        #pragma unroll
        for (int i2 = 0; i2 < 2; i2++)
            #pragma unroll
            for (int q = 0; q < 16; q++) {
                float ov = __shfl_xor(best[i2][q], off);
                int   oi = __shfl_xor(bidx[i2][q], off);
                if (ov < best[i2][q] || (ov == best[i2][q] && oi < bidx[i2][q])) {
                    best[i2][q] = ov; bidx[i2][q] = oi;
                }
            }
    }
    if (r32 == 0) {            // lanes 0 and 32 per wave
        #pragma unroll
        for (int i2 = 0; i2 < 2; i2++)
            #pragma unroll
            for (int q = 0; q < 16; q++) {
                int row = i2 * 32 + ((q & 3) + 8 * (q >> 2) + 4 * h);
                cand_v[row * 4 + wn] = best[i2][q];
                cand_i[row * 4 + wn] = bidx[i2][q];
            }
    }
    __syncthreads();           // cand final; all zero-stores drained (vmcnt 0)
    if (tid < 64) {            // final: 4 wn-candidates; tie -> lower idx
        float bv = cand_v[tid * 4 + 0];
        int   bi = cand_i[tid * 4 + 0];
        #pragma unroll
        for (int j = 1; j < 4; j++) {
            float v = cand_v[tid * 4 + j];
            int   ii = cand_i[tid * 4 + j];
            if (v < bv || (v == bv && ii < bi)) { bv = v; bi = ii; }
        }
        ids[tid] = bi;
        out_idx[m0 + tid] = bi;
        out[O_IDX + m0 + tid] = (float)bi;
        atomicAdd(&hist[bi], 1);
        if constexpr (WE)
            out[O_MINENC + (size_t)(m0 + tid) * NE + bi] = 1.0f;
    }
    __syncthreads();           // ids visible

    // ---- fused gather: z_q_st for our 64 rows + loss partial ----
    float s = 0.0f;
    #pragma unroll
    for (int j = 0; j < 4; j++) {              // 1024 8-float units / 256 threads
        int u = j * 256 + tid;
        int r = u >> 4, sub = u & 15;
        int id = ids[r];
        const float* zr = z + (size_t)(m0 + r) * EDIM + sub * 8;
        const float* er = emb + (size_t)id * EDIM + sub * 8;
        float* outr = out + O_ZQ + (size_t)(m0 + r) * EDIM + sub * 8;
        float4 z0 = reinterpret_cast<const float4*>(zr)[0];
        float4 z1 = reinterpret_cast<const float4*>(zr)[1];
        float4 e0 = reinterpret_cast<const float4*>(er)[0];
        float4 e1 = reinterpret_cast<const float4*>(er)[1];
        float zz[8] = {z0.x, z0.y, z0.z, z0.w, z1.x, z1.y, z1.z, z1.w};
        float ee[8] = {e0.x, e0.y, e0.z, e0.w, e1.x, e1.y, e1.z, e1.w};
        #pragma unroll
        for (int jj = 0; jj < 8; jj++) {
            float d = ee[jj] - zz[jj];
            outr[jj] = zz[jj] + d;             // match reference rounding
            s += d * d;
        }
    }
    red[tid] = s;
    __syncthreads();
    #pragma unroll
    for (int o = 128; o >= 1; o >>= 1) {
        if (tid < o) red[tid] += red[tid + o];
        __syncthreads();
    }
    if (tid == 0) part[blockIdx.x] = red[0];
}

// ---------------- min_encodings one-hot fill (fallback path only) ----------------
__global__ __launch_bounds__(256) void minenc_kernel(const int* __restrict__ idx,
                                                     float* __restrict__ out) {
    size_t i = (size_t)blockIdx.x * blockDim.x + threadIdx.x;
    const size_t total = (size_t)M_ROWS * (NE / 2);
    const size_t stride = (size_t)gridDim.x * blockDim.x;
    for (; i < total; i += stride) {
        int row = (int)(i >> 10);
        int col = (int)(i & 1023) << 1;
        int id = idx[row];
        float2 v;
        v.x = (col == id) ? 1.0f : 0.0f;
        v.y = (col + 1 == id) ? 1.0f : 0.0f;
        reinterpret_cast<float2*>(out)[i] = v;
    }
}

// ---------------- finalize: loss + perplexity (512 partials) ----------------------
__global__ __launch_bounds__(256) void finalize_kernel(const float* __restrict__ partial,
                                                       const int* __restrict__ hist,
                                                       float* __restrict__ out) {
    __shared__ float red[256];
    const int tid = threadIdx.x;
    float s = partial[tid] + partial[tid + 256];
    red[tid] = s;
    __syncthreads();
    #pragma unroll
    for (int o = 128; o >= 1; o >>= 1) {
        if (tid < o) red[tid] += red[tid + o];
        __syncthreads();
    }
    if (tid == 0) out[O_LOSS] = 1.25f * red[0] / (float)((size_t)M_ROWS * EDIM);
    __syncthreads();

    float h = 0.0f;
    for (int i = 0; i < 8; i++) {
        float p = (float)hist[tid * 8 + i] * (1.0f / (float)M_ROWS);
        h += p * logf(p + 1e-10f);
    }
    red[tid] = h;
    __syncthreads();
    #pragma unroll
    for (int o = 128; o >= 1; o >>= 1) {
        if (tid < o) red[tid] += red[tid + o];
        __syncthreads();
    }
    if (tid == 0) out[O_PERP] = expf(-red[0]);
}

extern "C" void kernel_launch(void* const* d_in, const int* in_sizes, int n_in,
                              void* d_out, int out_size, void* d_ws, size_t ws_size,
                              hipStream_t stream) {
    const float* z   = (const float*)d_in[0];
    const float* emb = (const float*)d_in[1];
    float* out = (float*)d_out;

    char* ws = (char*)d_ws;
    float* eq    = (float*)ws;                    // 2048 f32
    int*   idx   = (int*)(ws + 8192);             // 32768 i32
    int*   hist  = (int*)(ws + 139264);           // 2048 i32
    float* part  = (float*)(ws + 147456);         // 512 f32
    float* zsums = (float*)(ws + 155648);         // 32768 f32

    const bool big_ws = (ws_size >= (size_t)(40u << 20));   // fixed per session
    u16 *Z2, *E2P;
    if (big_ws) {                                 // planes + packed B in scratch
        Z2  = (u16*)(ws + (4u << 20));            // 16 MB (2 planes)
        E2P = (u16*)(ws + (24u << 20));           // 1 MB packed B-frags
    } else {                                      // fallback: use minenc region,
        Z2  = (u16*)(out + O_MINENC + 2);         // minenc kernel rewrites after
        E2P = Z2 + 2 * (size_t)ZPLANE2;
    }

    prep_z_kernel<<<2048, 256, 0, stream>>>(z, Z2, zsums);
    prep_e_kernel<<<NE, 64, 0, stream>>>(emb, eq, hist, E2P);
    if (big_ws) {
        argmin_mfma_kernel<1><<<512, 256, 0, stream>>>(Z2, E2P, zsums, eq, idx, out, hist, z, emb, part);
    } else {
        argmin_mfma_kernel<0><<<512, 256, 0, stream>>>(Z2, E2P, zsums, eq, idx, out, hist, z, emb, part);
        minenc_kernel<<<8192, 256, 0, stream>>>(idx, out + O_MINENC);
    }
    finalize_kernel<<<1, 256, 0, stream>>>(part, hist, out);
}

// Round 20
// 100.597 us; speedup vs baseline: 1.7276x; 1.3361x over previous
//
#include <hip/hip_runtime.h>
#include <hip/hip_bf16.h>
#include <hip/hip_fp16.h>
#include <math.h>

#define M_ROWS 32768
#define NE 2048
#define EDIM 128

// d_out element offsets (fp32)
#define O_LOSS 0
#define O_ZQ 1
#define O_PERP 4194305
#define O_MINENC 4194306
#define O_IDX 71303170ll

typedef unsigned short u16;
typedef __attribute__((ext_vector_type(8))) _Float16 half8;        // 8 f16 (4 VGPRs)
typedef __attribute__((ext_vector_type(8))) unsigned short ushort8;
typedef __attribute__((ext_vector_type(16))) float f32x16;         // 32x32 MFMA acc

// ---------------- prep_e: eq (bit-identical tree) + hist zero + e2p pack ---------
// (verified rounds 15-19) e' = 2048*e = eh + em + r'; e2p layout proven 11-19:
// [strip n/32][j k/16][lv][(k8-half)*32+(n&31)][k&7]
__global__ void prep_e_kernel(const float* __restrict__ emb, float* __restrict__ eq,
                              int* __restrict__ hist, u16* __restrict__ e2p) {
    const int n = blockIdx.x;
    const int lane = threadIdx.x;
    float v0 = emb[(size_t)n * EDIM + lane];
    float v1 = emb[(size_t)n * EDIM + 64 + lane];
    float s = v0 * v0 + v1 * v1;
    #pragma unroll
    for (int off = 32; off >= 1; off >>= 1) s += __shfl_down(s, off);
    if (lane == 0) { eq[n] = s; hist[n] = 0; }

    if (lane < 32) {
        const int k = lane * 4;
        float4 e4 = reinterpret_cast<const float4*>(emb + (size_t)n * EDIM + k)[0];
        float fv[4] = {e4.x * 2048.0f, e4.y * 2048.0f, e4.z * 2048.0f, e4.w * 2048.0f};
        u16 hs[4], ms[4];
        #pragma unroll
        for (int j = 0; j < 4; j++) {
            __half hh = __float2half_rn(fv[j]);
            float fh = __half2float(hh);
            float r = fv[j] - fh;                  // exact
            __half hm = __float2half_rn(r);
            hs[j] = __half_as_ushort(hh);
            ms[j] = __half_as_ushort(hm);
        }
        const int strip = n >> 5, r32n = n & 31;
        const int jj = k >> 4, hh2 = (k >> 3) & 1, slot4 = k & 7;
        size_t base = ((size_t)(strip * 8 + jj) * 2) * 512 + (size_t)(hh2 * 32 + r32n) * 8 + slot4;
        reinterpret_cast<ushort4*>(e2p + base)[0]       = make_ushort4(hs[0], hs[1], hs[2], hs[3]);
        reinterpret_cast<ushort4*>(e2p + base + 512)[0] = make_ushort4(ms[0], ms[1], ms[2], ms[3]);
    }
}

// ---------------- MFMA argmin: round-16 core + in-block z staging ----------------
// EXACT round-16 (110.7us) structure: 256 thr, launch_bounds(256,2), 2 blocks/CU,
// #pragma unroll 4 j-loop (limits B-load hoisting -- rounds 12/15 spill lesson),
// per-tt interleaved zero-fill AFTER the j-loop (round-19 proved bulk-hoisting is
// worse: 63-deep vmcnt queue turns a 512KB burst into a serial stall).
// ONE change: z staged fp32->fp16^2 IN-BLOCK (round-15-verified staging block) --
// kills the prep_z kernel and the 82MB z2 HBM round-trip. zsums computed in-block
// (fp32 any-order class: grid-multiple-shift invariance, validated across three
// summation orders in rounds 2-19). Value path otherwise BIT-IDENTICAL.
template<int WE>
__global__ __launch_bounds__(256, 2) void argmin_mfma_kernel(
    const u16* __restrict__ e2p, const float* __restrict__ eq,
    int* __restrict__ out_idx, float* __restrict__ out, int* __restrict__ hist,
    const float* __restrict__ z, const float* __restrict__ emb,
    float* __restrict__ part)
{
    __shared__ __align__(16) u16 zs[16384];     // 32 KB: [lv][kc16][row64][8]
    __shared__ float zsl[64];
    __shared__ float cand_v[256];
    __shared__ int   cand_i[256];
    __shared__ int   ids[64];
    __shared__ float red[256];

    const int tid = threadIdx.x;
    const int w = tid >> 6, l = tid & 63;
    const int wn = w;                   // col quarter within the 128-col tt tile
    const int h = l >> 5, r32 = l & 31;
    const int m0 = blockIdx.x * 64;

    // ---- in-block z staging + zsums (round-15-verified block) ----
    {
        float zsp = 0.0f;
        #pragma unroll
        for (int p = 0; p < 4; p++) {
            const int s = p * 256 + tid;    // slot = kc*64 + row (16B units)
            const int row = s & 63;         // == tid & 63 for every p
            const int kc = s >> 6;
            const float* zp = z + (size_t)(m0 + row) * EDIM + kc * 8;
            float4 u0 = reinterpret_cast<const float4*>(zp)[0];
            float4 u1 = reinterpret_cast<const float4*>(zp)[1];
            float f[8] = {u0.x, u0.y, u0.z, u0.w, u1.x, u1.y, u1.z, u1.w};
            ushort8 hv, mv;
            #pragma unroll
            for (int j = 0; j < 8; j++) {
                zsp += f[j] * f[j];                    // k-ascending within thread
                __half hh = __float2half_rn(f[j]);
                float fh = __half2float(hh);
                float r = f[j] - fh;                   // exact
                __half hm = __float2half_rn(r);
                hv[j] = __half_as_ushort(hh);
                mv[j] = __half_as_ushort(hm);
            }
            *reinterpret_cast<ushort8*>(zs + (size_t)s * 8) = hv;          // lv0
            *reinterpret_cast<ushort8*>(zs + 8192 + (size_t)s * 8) = mv;   // lv1
        }
        red[tid] = zsp;
    }
    __syncthreads();
    if (tid < 64) zsl[tid] = red[tid] + red[tid + 64] + red[tid + 128] + red[tid + 192];
    __syncthreads();

    float best[2][16];
    int   bidx[2][16];
    #pragma unroll
    for (int i2 = 0; i2 < 2; i2++)
        #pragma unroll
        for (int q = 0; q < 16; q++) { best[i2][q] = 3.4e38f; bidx[i2][q] = 0; }

    float2* me2 = reinterpret_cast<float2*>(out + O_MINENC + (size_t)m0 * NE);

    for (int tt = 0; tt < 16; tt++) {           // 16 t-tiles x 128 cols
        const int strip = tt * 4 + wn;
        const u16* bb = e2p + ((size_t)strip * 16) * 512 + (size_t)l * 8;
        const int n = tt * 128 + wn * 32 + r32;
        const float eqv = eq[n];                // hoisted: issued before stores

        f32x16 am[2], ac[2];
        #pragma unroll
        for (int i2 = 0; i2 < 2; i2++)
            #pragma unroll
            for (int q = 0; q < 16; q++) { am[i2][q] = 0.0f; ac[i2][q] = 0.0f; }

        #pragma unroll 4
        for (int j = 0; j < 8; j++) {           // K=16 per step, k ascending
            half8 b0 = *reinterpret_cast<const half8*>(bb + (size_t)(j * 2 + 0) * 512);
            half8 b1 = *reinterpret_cast<const half8*>(bb + (size_t)(j * 2 + 1) * 512);
            half8 a00 = *reinterpret_cast<const half8*>(zs + ((0 * 16 + j * 2 + h) * 64 + 0 * 32 + r32) * 8);
            half8 a01 = *reinterpret_cast<const half8*>(zs + ((1 * 16 + j * 2 + h) * 64 + 0 * 32 + r32) * 8);
            half8 a10 = *reinterpret_cast<const half8*>(zs + ((0 * 16 + j * 2 + h) * 64 + 1 * 32 + r32) * 8);
            half8 a11 = *reinterpret_cast<const half8*>(zs + ((1 * 16 + j * 2 + h) * 64 + 1 * 32 + r32) * 8);

            am[0] = __builtin_amdgcn_mfma_f32_32x32x16_f16(a00, b0, am[0], 0, 0, 0);
            ac[0] = __builtin_amdgcn_mfma_f32_32x32x16_f16(a00, b1, ac[0], 0, 0, 0);
            ac[0] = __builtin_amdgcn_mfma_f32_32x32x16_f16(a01, b0, ac[0], 0, 0, 0);
            am[1] = __builtin_amdgcn_mfma_f32_32x32x16_f16(a10, b0, am[1], 0, 0, 0);
            ac[1] = __builtin_amdgcn_mfma_f32_32x32x16_f16(a10, b1, ac[1], 0, 0, 0);
            ac[1] = __builtin_amdgcn_mfma_f32_32x32x16_f16(a11, b0, ac[1], 0, 0, 0);
        }

        if constexpr (WE) {                     // stores AFTER this tt's B loads
            const float2 zz2 = make_float2(0.0f, 0.0f);
            #pragma unroll
            for (int jj = 0; jj < 16; jj++)
                me2[tt * 4096 + jj * 256 + tid] = zz2;
        }

        // online argmin update (n ascending across tt; strict <) -- covers stores
        #pragma unroll
        for (int i2 = 0; i2 < 2; i2++) {
            #pragma unroll
            for (int q = 0; q < 16; q++) {
                const int row = i2 * 32 + ((q & 3) + 8 * (q >> 2) + 4 * h);
                float zse = zsl[row] + eqv;              // fp32 round at ~128 scale
                float dotp = am[i2][q] + ac[i2][q];      // one round
                float val = zse - dotp * 0.0009765625f;  // *2^-10 exact; one round
                if (val < best[i2][q]) { best[i2][q] = val; bidx[i2][q] = n; }
            }
        }
    }

    // reduce over the 32 col-lanes (offs <32 stay within each half)
    #pragma unroll
    for (int off = 16; off >= 1; off >>= 1) {
        #pragma unroll
        for (int i2 = 0; i2 < 2; i2++)
            #pragma unroll
            for (int q = 0; q < 16; q++) {
                float ov = __shfl_xor(best[i2][q], off);
                int   oi = __shfl_xor(bidx[i2][q], off);
                if (ov < best[i2][q] || (ov == best[i2][q] && oi < bidx[i2][q])) {
                    best[i2][q] = ov; bidx[i2][q] = oi;
                }
            }
    }
    if (r32 == 0) {            // lanes 0 and 32 per wave
        #pragma unroll
        for (int i2 = 0; i2 < 2; i2++)
            #pragma unroll
            for (int q = 0; q < 16; q++) {
                int row = i2 * 32 + ((q & 3) + 8 * (q >> 2) + 4 * h);
                cand_v[row * 4 + wn] = best[i2][q];
                cand_i[row * 4 + wn] = bidx[i2][q];
            }
    }
    __syncthreads();           // cand final; all zero-stores drained (vmcnt 0)
    if (tid < 64) {            // final: 4 wn-candidates; tie -> lower idx
        float bv = cand_v[tid * 4 + 0];
        int   bi = cand_i[tid * 4 + 0];
        #pragma unroll
        for (int j = 1; j < 4; j++) {
            float v = cand_v[tid * 4 + j];
            int   ii = cand_i[tid * 4 + j];
            if (v < bv || (v == bv && ii < bi)) { bv = v; bi = ii; }
        }
        ids[tid] = bi;
        out_idx[m0 + tid] = bi;
        out[O_IDX + m0 + tid] = (float)bi;
        atomicAdd(&hist[bi], 1);
        if constexpr (WE)
            out[O_MINENC + (size_t)(m0 + tid) * NE + bi] = 1.0f;
    }
    __syncthreads();           // ids visible

    // ---- fused gather: z_q_st for our 64 rows + loss partial ----
    float s = 0.0f;
    #pragma unroll
    for (int j = 0; j < 4; j++) {              // 1024 8-float units / 256 threads
        int u = j * 256 + tid;
        int r = u >> 4, sub = u & 15;
        int id = ids[r];
        const float* zr = z + (size_t)(m0 + r) * EDIM + sub * 8;
        const float* er = emb + (size_t)id * EDIM + sub * 8;
        float* outr = out + O_ZQ + (size_t)(m0 + r) * EDIM + sub * 8;
        float4 z0 = reinterpret_cast<const float4*>(zr)[0];
        float4 z1 = reinterpret_cast<const float4*>(zr)[1];
        float4 e0 = reinterpret_cast<const float4*>(er)[0];
        float4 e1 = reinterpret_cast<const float4*>(er)[1];
        float zz[8] = {z0.x, z0.y, z0.z, z0.w, z1.x, z1.y, z1.z, z1.w};
        float ee[8] = {e0.x, e0.y, e0.z, e0.w, e1.x, e1.y, e1.z, e1.w};
        #pragma unroll
        for (int jj = 0; jj < 8; jj++) {
            float d = ee[jj] - zz[jj];
            outr[jj] = zz[jj] + d;             // match reference rounding
            s += d * d;
        }
    }
    red[tid] = s;
    __syncthreads();
    #pragma unroll
    for (int o = 128; o >= 1; o >>= 1) {
        if (tid < o) red[tid] += red[tid + o];
        __syncthreads();
    }
    if (tid == 0) part[blockIdx.x] = red[0];
}

// ---------------- min_encodings one-hot fill (fallback path only) ----------------
__global__ __launch_bounds__(256) void minenc_kernel(const int* __restrict__ idx,
                                                     float* __restrict__ out) {
    size_t i = (size_t)blockIdx.x * blockDim.x + threadIdx.x;
    const size_t total = (size_t)M_ROWS * (NE / 2);
    const size_t stride = (size_t)gridDim.x * blockDim.x;
    for (; i < total; i += stride) {
        int row = (int)(i >> 10);
        int col = (int)(i & 1023) << 1;
        int id = idx[row];
        float2 v;
        v.x = (col == id) ? 1.0f : 0.0f;
        v.y = (col + 1 == id) ? 1.0f : 0.0f;
        reinterpret_cast<float2*>(out)[i] = v;
    }
}

// ---------------- finalize: loss + perplexity (512 partials) ----------------------
__global__ __launch_bounds__(256) void finalize_kernel(const float* __restrict__ partial,
                                                       const int* __restrict__ hist,
                                                       float* __restrict__ out) {
    __shared__ float red[256];
    const int tid = threadIdx.x;
    float s = partial[tid] + partial[tid + 256];
    red[tid] = s;
    __syncthreads();
    #pragma unroll
    for (int o = 128; o >= 1; o >>= 1) {
        if (tid < o) red[tid] += red[tid + o];
        __syncthreads();
    }
    if (tid == 0) out[O_LOSS] = 1.25f * red[0] / (float)((size_t)M_ROWS * EDIM);
    __syncthreads();

    float h = 0.0f;
    for (int i = 0; i < 8; i++) {
        float p = (float)hist[tid * 8 + i] * (1.0f / (float)M_ROWS);
        h += p * logf(p + 1e-10f);
    }
    red[tid] = h;
    __syncthreads();
    #pragma unroll
    for (int o = 128; o >= 1; o >>= 1) {
        if (tid < o) red[tid] += red[tid + o];
        __syncthreads();
    }
    if (tid == 0) out[O_PERP] = expf(-red[0]);
}

extern "C" void kernel_launch(void* const* d_in, const int* in_sizes, int n_in,
                              void* d_out, int out_size, void* d_ws, size_t ws_size,
                              hipStream_t stream) {
    const float* z   = (const float*)d_in[0];
    const float* emb = (const float*)d_in[1];
    float* out = (float*)d_out;

    char* ws = (char*)d_ws;
    float* eq    = (float*)ws;                    // 2048 f32
    int*   idx   = (int*)(ws + 8192);             // 32768 i32
    int*   hist  = (int*)(ws + 139264);           // 2048 i32
    float* part  = (float*)(ws + 147456);         // 512 f32

    const bool big_ws = (ws_size >= (size_t)(8u << 20));    // fixed per session
    u16* E2P;
    if (big_ws) {
        E2P = (u16*)(ws + (4u << 20));            // 1 MB packed B-frags in scratch
    } else {                                      // fallback: park e2p in the minenc
        E2P = (u16*)(out + O_MINENC + 2);         // region; minenc kernel rewrites it
    }

    prep_e_kernel<<<NE, 64, 0, stream>>>(emb, eq, hist, E2P);
    if (big_ws) {
        argmin_mfma_kernel<1><<<512, 256, 0, stream>>>(E2P, eq, idx, out, hist, z, emb, part);
    } else {
        argmin_mfma_kernel<0><<<512, 256, 0, stream>>>(E2P, eq, idx, out, hist, z, emb, part);
        minenc_kernel<<<8192, 256, 0, stream>>>(idx, out + O_MINENC);
    }
    finalize_kernel<<<1, 256, 0, stream>>>(part, hist, out);
}